// Round 9
// baseline (785.549 us; speedup 1.0000x reference)
//
#include <hip/hip_runtime.h>
#include <hip/hip_bf16.h>

#define M_ROWS 12000
#define K_PAD  12032          // 188 * 64
#define FEAT   256
#define NCLS   40
#define NSLICE 5
#define NTILES 188            // K-tiles of 64
#define NBM    47             // M-tiles of 256
#define PSLABE (M_ROWS * FEAT)         // elements per P slab (bf16)
#define TILE_SHORTS 16384              // 32 KB tile image
#define HALF_SHORTS 8192

typedef __attribute__((ext_vector_type(4))) float f32x4;
typedef __attribute__((ext_vector_type(8))) short s16x8;
typedef __attribute__((ext_vector_type(4))) short s16x4;
typedef unsigned int u32;

__device__ __forceinline__ short f2bf(float f){
  __hip_bfloat16 h = __float2bfloat16(f);
  union { __hip_bfloat16 h; short s; } u; u.h = h; return u.s;
}
__device__ __forceinline__ float bf2f(short s){
  union { float f; u32 u; } v; v.u = ((u32)(unsigned short)s) << 16; return v.f;
}

__device__ __forceinline__ f32x4 mfma16(s16x8 a, s16x8 b, f32x4 c){
  return __builtin_amdgcn_mfma_f32_16x16x32_bf16(a, b, c, 0, 0, 0);
}

__device__ __forceinline__ void gl16(const void* g, void* l){
  __builtin_amdgcn_global_load_lds(
      (const __attribute__((address_space(1))) u32*)g,
      (__attribute__((address_space(3))) u32*)l, 16, 0, 0);
}

#define VM4   do { asm volatile("s_waitcnt vmcnt(4)" ::: "memory"); \
                   __builtin_amdgcn_sched_barrier(0); } while(0)
#define VM0   do { asm volatile("s_waitcnt vmcnt(0)" ::: "memory"); \
                   __builtin_amdgcn_sched_barrier(0); } while(0)
#define BARR  do { __builtin_amdgcn_s_barrier(); \
                   __builtin_amdgcn_sched_barrier(0); } while(0)

__device__ __forceinline__ int swz(int r){ return (r & 3) ^ ((r >> 2) & 3); }

// ---------------------------------------------------------------------------
// Pack adj fp32 -> per-(bm,tile) 32 KB bf16 images, swizzle baked in.
// (unchanged from round 8)
// ---------------------------------------------------------------------------
__global__ __launch_bounds__(256) void k_pack(const float* __restrict__ adj,
                                              short* __restrict__ Apack){
  __shared__ short stage[8][264];   // 8 rows x 256 bf16 (+pad)
  const int tg = blockIdx.x;        // 0..46  (tiles 4tg..4tg+3)
  const int bm = blockIdx.y;        // 0..46
  const int t  = threadIdx.x;

  const int rlr = t >> 5;
  const int rc  = (t & 31) * 8;
  const int csrc = tg * 256 + rc;
  const int g2  = t >> 5;
  const int wtl = g2 >> 1, wh = g2 & 1;
  const int wri = (t >> 2) & 7, wsl = t & 3;
  short* wbase = Apack + ((size_t)bm * NTILES + 4*tg + wtl) * TILE_SHORTS
               + wh * HALF_SHORTS;

  for (int it = 0; it < 32; ++it){
    const int r0 = it * 8;
    {
      int grow = bm*256 + r0 + rlr; if (grow > M_ROWS - 1) grow = M_ROWS - 1;
      s16x8 o;
      if (csrc < M_ROWS){
        const float* sp = adj + (size_t)grow * M_ROWS + csrc;
        f32x4 f0 = *(const f32x4*)(sp);
        f32x4 f1 = *(const f32x4*)(sp + 4);
        #pragma unroll
        for (int j = 0; j < 4; ++j){ o[j] = f2bf(f0[j]); o[4+j] = f2bf(f1[j]); }
      } else {
        o = (s16x8)0;
      }
      *(s16x8*)&stage[rlr][rc] = o;
    }
    __syncthreads();
    {
      const int rl = r0 + wri;
      const int sw = swz(rl);
      const int scol = wtl*64 + wh*32 + ((wsl ^ sw) * 8);
      s16x8 o = *(const s16x8*)&stage[wri][scol];
      *(s16x8*)(wbase + rl*32 + wsl*8) = o;
    }
    __syncthreads();
  }
}

// ---------------------------------------------------------------------------
// fp32 x [12000][256] -> Bpack tile images (transposed, swizzle baked in).
// ---------------------------------------------------------------------------
__global__ __launch_bounds__(256) void k_transpose_pack(const float* __restrict__ src,
                                                        short* __restrict__ Bpack){
  const int t = threadIdx.x;
  if (blockIdx.x == 375){   // zero pad: k in [12000,12032)
    short* d = Bpack + (size_t)187 * TILE_SHORTS + HALF_SHORTS + t * 32;
    s16x8 z = (s16x8)0;
    #pragma unroll
    for (int i = 0; i < 4; ++i) *(s16x8*)(d + 8*i) = z;
    return;
  }
  __shared__ float tile[32][257];
  const int r0 = blockIdx.x * 32;     // k-base
  {
    const int r = t >> 3, cs = (t & 7) * 32;
    const float* s = src + (size_t)(r0 + r) * FEAT + cs;
    #pragma unroll
    for (int i = 0; i < 8; ++i){
      f32x4 v = *(const f32x4*)(s + 4*i);
      tile[r][cs + 4*i + 0] = v[0];
      tile[r][cs + 4*i + 1] = v[1];
      tile[r][cs + 4*i + 2] = v[2];
      tile[r][cs + 4*i + 3] = v[3];
    }
  }
  __syncthreads();
  const int c = t;                    // output column 0..255
  const int kt = r0 >> 6, hh = (r0 >> 5) & 1, sc = swz(c);
  short* d = Bpack + (size_t)kt * TILE_SHORTS + hh * HALF_SHORTS + c * 32;
  #pragma unroll
  for (int i = 0; i < 4; ++i){        // k group r0+8i..+7
    s16x8 o;
    #pragma unroll
    for (int j = 0; j < 8; ++j) o[j] = f2bf(tile[8*i + j][c]);
    *(s16x8*)(d + ((i ^ sc) * 8)) = o;
  }
}

// ---------------------------------------------------------------------------
// Big GEMM, 8-phase (unchanged from round 8); P output bf16.
// ---------------------------------------------------------------------------
__global__ __launch_bounds__(512, 2) void k_gemm8p(const short* __restrict__ Apack,
                                                   const short* __restrict__ Bpack,
                                                   short* __restrict__ Pbase){
  __shared__ __align__(16) short lds[2][4][8192];  // [dbuf][A0,A1,B0,B1]

  const int t = threadIdx.x;
  const int w = t >> 6, l = t & 63;
  const int wm = w >> 2, wn = w & 3;
  const int lr = l & 15, lg = l >> 4;

  // bijective XCD-chunked swizzle of flat block id (235 = 8*29+3)
  int id = blockIdx.x;
  {
    const int xcd = id & 7, idx = id >> 3;
    id = (xcd < 3 ? xcd * 30 : 90 + (xcd - 3) * 29) + idx;
  }
  const int bm = id % NBM, s = id / NBM;
  const int row0 = bm * 256;
  const int u0  = (s < 3) ? s * 38 : 114 + (s - 3) * 37;  // tile index
  const int nst = (s < 3) ? 38 : 37;

  const char* Ab = (const char*)(Apack + (size_t)bm * NTILES * TILE_SHORTS);
  const char* Bb = (const char*)Bpack;
  const size_t tp = (size_t)t * 16;   // per-lane source offset within half-image

#define ST_AH(q, h, kt) do{                                                   \
    const char* s_ = Ab + (size_t)(kt) * 32768 + (h) * 16384 + tp;            \
    gl16(s_,        (char*)&lds[q][h][0] + w*1024);                           \
    gl16(s_ + 8192, (char*)&lds[q][h][0] + 8192 + w*1024); }while(0)
#define ST_BH(q, h, kt) do{                                                   \
    const char* s_ = Bb + (size_t)(kt) * 32768 + (h) * 16384 + tp;            \
    gl16(s_,        (char*)&lds[q][2+(h)][0] + w*1024);                       \
    gl16(s_ + 8192, (char*)&lds[q][2+(h)][0] + 8192 + w*1024); }while(0)

#define AF(q, h, mf) \
    (*(const s16x8*)&lds[q][h][ (wm*128 + (mf)*16 + lr) * 32 + \
      ((lg ^ swz(wm*128 + (mf)*16 + lr)) * 8) ])
#define BF(q, h, nf) \
    (*(const s16x8*)&lds[q][2+(h)][ (wn*64 + (nf)*16 + lr) * 32 + \
      ((lg ^ swz(wn*64 + (nf)*16 + lr)) * 8) ])

  f32x4 acc[8][4];
  #pragma unroll
  for (int m = 0; m < 8; ++m)
    #pragma unroll
    for (int n = 0; n < 4; ++n) acc[m][n] = (f32x4)(0.0f);

  // prologue: stage tile 0 (order Bk0, Ak0, Bk1, Ak1)
  ST_BH(0, 0, u0); ST_AH(0, 0, u0);
  ST_BH(0, 1, u0); ST_AH(0, 1, u0);
  VM4;    // Bk0+Ak0 landed; k1 halves stay in flight
  BARR;

  for (int t2 = 0; t2 < nst; ++t2){
    const int q = t2 & 1, qn = q ^ 1;
    const bool stg = (t2 + 1 < nst);
    const int ktn = u0 + t2 + 1;

    s16x8 bfr[4], af[4];

    // ---- P0: k0, m0-3 (+B reads); stage B-k0(next) ----
    #pragma unroll
    for (int n = 0; n < 4; ++n) bfr[n] = BF(q, 0, n);
    #pragma unroll
    for (int m = 0; m < 4; ++m) af[m] = AF(q, 0, m);
    if (stg) ST_BH(qn, 0, ktn);
    BARR;
    __builtin_amdgcn_s_setprio(1);
    #pragma unroll
    for (int m = 0; m < 4; ++m)
      #pragma unroll
      for (int n = 0; n < 4; ++n)
        acc[m][n] = mfma16(af[m], bfr[n], acc[m][n]);
    __builtin_amdgcn_s_setprio(0);
    BARR;

    // ---- P1: k0, m4-7 (B reused); stage A-k0(next) ----
    #pragma unroll
    for (int m = 0; m < 4; ++m) af[m] = AF(q, 0, m + 4);
    if (stg) ST_AH(qn, 0, ktn);
    BARR;
    __builtin_amdgcn_s_setprio(1);
    #pragma unroll
    for (int m = 0; m < 4; ++m)
      #pragma unroll
      for (int n = 0; n < 4; ++n)
        acc[m + 4][n] = mfma16(af[m], bfr[n], acc[m + 4][n]);
    __builtin_amdgcn_s_setprio(0);
    if (stg) { VM4; } else { VM0; }   // this tile's k1 halves landed
    BARR;

    // ---- P2: k1, m0-3 (+B reads); stage B-k1(next) ----
    #pragma unroll
    for (int n = 0; n < 4; ++n) bfr[n] = BF(q, 1, n);
    #pragma unroll
    for (int m = 0; m < 4; ++m) af[m] = AF(q, 1, m);
    if (stg) ST_BH(qn, 1, ktn);
    BARR;
    __builtin_amdgcn_s_setprio(1);
    #pragma unroll
    for (int m = 0; m < 4; ++m)
      #pragma unroll
      for (int n = 0; n < 4; ++n)
        acc[m][n] = mfma16(af[m], bfr[n], acc[m][n]);
    __builtin_amdgcn_s_setprio(0);
    BARR;

    // ---- P3: k1, m4-7 (B reused); stage A-k1(next) ----
    #pragma unroll
    for (int m = 0; m < 4; ++m) af[m] = AF(q, 1, m + 4);
    if (stg) ST_AH(qn, 1, ktn);
    BARR;
    __builtin_amdgcn_s_setprio(1);
    #pragma unroll
    for (int m = 0; m < 4; ++m)
      #pragma unroll
      for (int n = 0; n < 4; ++n)
        acc[m + 4][n] = mfma16(af[m], bfr[n], acc[m + 4][n]);
    __builtin_amdgcn_s_setprio(0);
    if (stg) { VM4; }                 // next tile's k0 halves landed
    BARR;
  }
#undef ST_AH
#undef ST_BH
#undef AF
#undef BF

  // epilogue: C/D layout col=lane&15, row=(lane>>4)*4+reg ; bf16 stores
  short* P = Pbase + (size_t)s * PSLABE;
  #pragma unroll
  for (int m = 0; m < 8; ++m){
    const int row = row0 + wm*128 + m*16 + lg*4;
    #pragma unroll
    for (int n = 0; n < 4; ++n){
      const int col = wn*64 + n*16 + lr;
      short* pp = P + (size_t)row * FEAT + col;
      #pragma unroll
      for (int r = 0; r < 4; ++r)
        if (row + r < M_ROWS) pp[(size_t)r * FEAT] = f2bf(acc[m][n][r]);
    }
  }
}

// ---------------------------------------------------------------------------
// Bpack = pack(transpose(l2norm_rows(relu((sum_s P[s]) @ W + b))))  (P bf16)
// ---------------------------------------------------------------------------
__global__ __launch_bounds__(256) void k_fused2(const short* __restrict__ Pb,
                                                const float* __restrict__ W,
                                                const float* __restrict__ b,
                                                short* __restrict__ Bpack){
  __shared__ float ylds[32][257];
  __shared__ float red[32][33];
  __shared__ float scale[32];
  const int t  = threadIdx.x;
  const int r0 = blockIdx.x * 32;     // output k-base (H row block)
  {
    const int r = t >> 3, cs = (t & 7) * 32;
    const size_t off = (size_t)(r0 + r) * FEAT + cs;
    float aa[32];
    {
      const short* p0 = Pb + off;
      #pragma unroll
      for (int i4 = 0; i4 < 4; ++i4){
        s16x8 v = *(const s16x8*)(p0 + i4*8);
        #pragma unroll
        for (int e = 0; e < 8; ++e) aa[i4*8 + e] = bf2f(v[e]);
      }
    }
    #pragma unroll
    for (int s = 1; s < NSLICE; ++s){
      const short* ps = Pb + (size_t)s * PSLABE + off;
      #pragma unroll
      for (int i4 = 0; i4 < 4; ++i4){
        s16x8 v = *(const s16x8*)(ps + i4*8);
        #pragma unroll
        for (int e = 0; e < 8; ++e) aa[i4*8 + e] += bf2f(v[e]);
      }
    }
    #pragma unroll
    for (int k = 0; k < 32; ++k) ylds[r][cs + k] = aa[k];
  }
  __syncthreads();

  const int rg = t >> 5;   // row group rg*4..+3 (k within block)
  const int cg = t & 31;   // col group cg*8..+7
  float acc[4][8];
  {
    float bias[8];
    #pragma unroll
    for (int j = 0; j < 8; ++j) bias[j] = b[cg*8 + j];
    #pragma unroll
    for (int i = 0; i < 4; ++i)
      #pragma unroll
      for (int j = 0; j < 8; ++j) acc[i][j] = bias[j];
  }

  #pragma unroll 4
  for (int k = 0; k < FEAT; ++k){
    float yv[4];
    #pragma unroll
    for (int i = 0; i < 4; ++i) yv[i] = ylds[rg*4 + i][k];
    f32x4 w0 = *(const f32x4*)(W + (size_t)k * FEAT + cg*8);
    f32x4 w1 = *(const f32x4*)(W + (size_t)k * FEAT + cg*8 + 4);
    #pragma unroll
    for (int i = 0; i < 4; ++i){
      #pragma unroll
      for (int j = 0; j < 4; ++j){
        acc[i][j]     += yv[i] * w0[j];
        acc[i][4 + j] += yv[i] * w1[j];
      }
    }
  }

  #pragma unroll
  for (int i = 0; i < 4; ++i){
    float ss = 0.0f;
    #pragma unroll
    for (int j = 0; j < 8; ++j){
      float v = fmaxf(acc[i][j], 0.0f);
      acc[i][j] = v;
      ss += v * v;
    }
    red[rg*4 + i][cg] = ss;
  }
  __syncthreads();
  if (t < 32){
    float ssum = 0.0f;
    #pragma unroll
    for (int j = 0; j < 32; ++j) ssum += red[t][j];
    scale[t] = 1.0f / fmaxf(sqrtf(ssum), 1e-12f);
  }
  __syncthreads();

  float sc[4];
  #pragma unroll
  for (int i = 0; i < 4; ++i) sc[i] = scale[rg*4 + i];

  // packed write: k = r0 + rg*4 + i, column c = cg*8 + j
  const int kb   = r0 + rg * 4;
  const int kt   = kb >> 6, hh = (kb >> 5) & 1, g = (kb >> 3) & 3, e0 = kb & 7;
  short* dbase = Bpack + (size_t)kt * TILE_SHORTS + hh * HALF_SHORTS;
  #pragma unroll
  for (int j = 0; j < 8; ++j){
    const int c = cg * 8 + j;
    s16x4 o;
    #pragma unroll
    for (int i = 0; i < 4; ++i) o[i] = f2bf(acc[i][j] * sc[i]);
    *(s16x4*)(dbase + c * 32 + ((g ^ swz(c)) * 8) + e0) = o;
  }
}

// ---------------------------------------------------------------------------
// out = (sum_s P[s]) @ W2 + b2    (12000 x 40), P bf16
// ---------------------------------------------------------------------------
__global__ __launch_bounds__(256) void k_final2(const short* __restrict__ Pb,
                                                const float* __restrict__ W2,
                                                const float* __restrict__ b2,
                                                float* __restrict__ out){
  __shared__ float ylds[32][257];
  const int t  = threadIdx.x;
  const int r0 = blockIdx.x * 32;
  {
    const int r = t >> 3, cs = (t & 7) * 32;
    const size_t off = (size_t)(r0 + r) * FEAT + cs;
    float aa[32];
    {
      const short* p0 = Pb + off;
      #pragma unroll
      for (int i4 = 0; i4 < 4; ++i4){
        s16x8 v = *(const s16x8*)(p0 + i4*8);
        #pragma unroll
        for (int e = 0; e < 8; ++e) aa[i4*8 + e] = bf2f(v[e]);
      }
    }
    #pragma unroll
    for (int s = 1; s < NSLICE; ++s){
      const short* ps = Pb + (size_t)s * PSLABE + off;
      #pragma unroll
      for (int i4 = 0; i4 < 4; ++i4){
        s16x8 v = *(const s16x8*)(ps + i4*8);
        #pragma unroll
        for (int e = 0; e < 8; ++e) aa[i4*8 + e] += bf2f(v[e]);
      }
    }
    #pragma unroll
    for (int k = 0; k < 32; ++k) ylds[r][cs + k] = aa[k];
  }
  __syncthreads();

  #pragma unroll
  for (int e = t; e < 32 * NCLS; e += 256){
    const int r = e / NCLS, n = e % NCLS;
    float a = b2[n];
    #pragma unroll 8
    for (int k = 0; k < FEAT; ++k)
      a = fmaf(ylds[r][k], W2[(size_t)k * NCLS + n], a);
    out[(size_t)(r0 + r) * NCLS + n] = a;
  }
}

// ---------------------------------------------------------------------------
// MEASUREMENT ROUND: each gemm launched TWICE (idempotent overwrite of P).
// dur_us - 556 = g0+g1+g2 decomposes the budget; no other changes vs r8.
// ---------------------------------------------------------------------------
extern "C" void kernel_launch(void* const* d_in, const int* in_sizes, int n_in,
                              void* d_out, int out_size, void* d_ws, size_t ws_size,
                              hipStream_t stream){
  const float* adj = (const float*)d_in[0];
  const float* x   = (const float*)d_in[1];
  const float* W0  = (const float*)d_in[2];
  const float* b0  = (const float*)d_in[3];
  const float* W1  = (const float*)d_in[4];
  const float* b1  = (const float*)d_in[5];
  const float* W2  = (const float*)d_in[6];
  const float* b2  = (const float*)d_in[7];
  float* out = (float*)d_out;

  char* ws = (char*)d_ws;
  const size_t BPACK_BYTES = (size_t)NTILES * TILE_SHORTS * 2;          //   6,160,384
  const size_t APACK_BYTES = (size_t)NBM * NTILES * TILE_SHORTS * 2;    // 289,538,048

  short* Bpack = (short*)ws;
  short* Apack = (short*)(ws + BPACK_BYTES);
  short* P     = (short*)(ws + BPACK_BYTES + APACK_BYTES);

  const dim3 b256(256), b512(512);

  k_pack<<<dim3(47, 47), b256, 0, stream>>>(adj, Apack);
  k_transpose_pack<<<376, b256, 0, stream>>>(x, Bpack);

  // layer 0 (gemm duplicated for timing decomposition)
  k_gemm8p<<<NBM * NSLICE, b512, 0, stream>>>(Apack, Bpack, P);
  k_gemm8p<<<NBM * NSLICE, b512, 0, stream>>>(Apack, Bpack, P);
  k_fused2<<<375, b256, 0, stream>>>(P, W0, b0, Bpack);
  // layer 1
  k_gemm8p<<<NBM * NSLICE, b512, 0, stream>>>(Apack, Bpack, P);
  k_gemm8p<<<NBM * NSLICE, b512, 0, stream>>>(Apack, Bpack, P);
  k_fused2<<<375, b256, 0, stream>>>(P, W1, b1, Bpack);
  // layer 2
  k_gemm8p<<<NBM * NSLICE, b512, 0, stream>>>(Apack, Bpack, P);
  k_gemm8p<<<NBM * NSLICE, b512, 0, stream>>>(Apack, Bpack, P);
  k_final2<<<375, b256, 0, stream>>>(P, W2, b2, out);
}

// Round 10
// 552.322 us; speedup vs baseline: 1.4223x; 1.4223x over previous
//
#include <hip/hip_runtime.h>
#include <hip/hip_bf16.h>

#define M_ROWS 12000
#define K_PAD  12032          // 188 * 64
#define FEAT   256
#define NCLS   40
#define NSLICE 5
#define NTILES 188            // K-tiles of 64
#define NBM    47             // M-tiles of 256
#define PSLABE (M_ROWS * FEAT)         // elements per P slab (bf16)
#define TILE_SHORTS 16384              // 32 KB tile image
#define HALF_SHORTS 8192

typedef __attribute__((ext_vector_type(4))) float f32x4;
typedef __attribute__((ext_vector_type(8))) short s16x8;
typedef __attribute__((ext_vector_type(4))) short s16x4;
typedef unsigned int u32;

__device__ __forceinline__ short f2bf(float f){
  __hip_bfloat16 h = __float2bfloat16(f);
  union { __hip_bfloat16 h; short s; } u; u.h = h; return u.s;
}
__device__ __forceinline__ float bf2f(short s){
  union { float f; u32 u; } v; v.u = ((u32)(unsigned short)s) << 16; return v.f;
}

__device__ __forceinline__ f32x4 mfma16(s16x8 a, s16x8 b, f32x4 c){
  return __builtin_amdgcn_mfma_f32_16x16x32_bf16(a, b, c, 0, 0, 0);
}

__device__ __forceinline__ void gl16(const void* g, void* l){
  __builtin_amdgcn_global_load_lds(
      (const __attribute__((address_space(1))) u32*)g,
      (__attribute__((address_space(3))) u32*)l, 16, 0, 0);
}

#define VM4   do { asm volatile("s_waitcnt vmcnt(4)" ::: "memory"); \
                   __builtin_amdgcn_sched_barrier(0); } while(0)
#define VM0   do { asm volatile("s_waitcnt vmcnt(0)" ::: "memory"); \
                   __builtin_amdgcn_sched_barrier(0); } while(0)
#define BARR  do { __builtin_amdgcn_s_barrier(); \
                   __builtin_amdgcn_sched_barrier(0); } while(0)

__device__ __forceinline__ int swz(int r){ return (r & 3) ^ ((r >> 2) & 3); }

// ---------------------------------------------------------------------------
// Pack adj fp32 -> per-(bm,tile) 32 KB bf16 images, swizzle baked in.
// gl16 double-buffered pipeline: issue next 8 rows into buf q^1 (counted
// vmcnt(2) - next iteration's loads stay in flight), barrier, then convert
// buf q and write 512 B contiguous image pieces. Images byte-identical to r8.
// ---------------------------------------------------------------------------
__global__ __launch_bounds__(256) void k_pack(const float* __restrict__ adj,
                                              short* __restrict__ Apack){
  __shared__ float stage[2][8][264];   // 264-float stride: rows rotate 8 banks
  const int tg = blockIdx.x;        // 0..46  (tiles 4tg..4tg+3)
  const int bm = blockIdx.y;        // 0..46
  const int t  = threadIdx.x;
  const int w  = t >> 6;

  // compute roles (identical mapping to r8)
  const int g2  = t >> 5;
  const int wtl = g2 >> 1, wh = g2 & 1;
  const int wri = (t >> 2) & 7, wsl = t & 3;
  short* wbase = Apack + ((size_t)bm * NTILES + 4*tg + wtl) * TILE_SHORTS
               + wh * HALF_SHORTS;

  // per-lane source col (clamped in-bounds; clamped lanes land only in the
  // k>=12000 pad region, which is zero on the B side)
  int csrc = tg * 256 + (t & 63) * 4;
  if (csrc > M_ROWS - 4) csrc = M_ROWS - 4;

  // prefetch iteration 0 into buf 0
  #pragma unroll
  for (int j = 0; j < 2; ++j){
    int gr = bm*256 + w*2 + j; if (gr > M_ROWS - 1) gr = M_ROWS - 1;
    gl16(adj + (size_t)gr * M_ROWS + csrc, &stage[0][w*2 + j][0]);
  }

  for (int it = 0; it < 32; ++it){
    const int q = it & 1;
    BARR;   // B1: prior compute done -> safe to overwrite buf q^1
    if (it + 1 < 32){
      #pragma unroll
      for (int j = 0; j < 2; ++j){
        int gr = bm*256 + (it+1)*8 + w*2 + j; if (gr > M_ROWS - 1) gr = M_ROWS - 1;
        gl16(adj + (size_t)gr * M_ROWS + csrc, &stage[q^1][w*2 + j][0]);
      }
      asm volatile("s_waitcnt vmcnt(2)" ::: "memory");
      __builtin_amdgcn_sched_barrier(0);
    } else {
      VM0;
    }
    BARR;   // B2: all waves' buf q landed
    // compute from buf q
    const int rl = it*8 + wri;
    const int sw = swz(rl);
    const float* sp = &stage[q][wri][wtl*64 + wh*32 + ((wsl ^ sw) * 8)];
    s16x8 o;
    #pragma unroll
    for (int e = 0; e < 8; ++e) o[e] = f2bf(sp[e]);
    *(s16x8*)(wbase + rl*32 + wsl*8) = o;
  }
}

// ---------------------------------------------------------------------------
// fp32 x [12000][256] -> Bpack tile images (transposed, swizzle baked in).
// ---------------------------------------------------------------------------
__global__ __launch_bounds__(256) void k_transpose_pack(const float* __restrict__ src,
                                                        short* __restrict__ Bpack){
  const int t = threadIdx.x;
  if (blockIdx.x == 375){   // zero pad: k in [12000,12032)
    short* d = Bpack + (size_t)187 * TILE_SHORTS + HALF_SHORTS + t * 32;
    s16x8 z = (s16x8)0;
    #pragma unroll
    for (int i = 0; i < 4; ++i) *(s16x8*)(d + 8*i) = z;
    return;
  }
  __shared__ float tile[32][257];
  const int r0 = blockIdx.x * 32;     // k-base
  {
    const int r = t >> 3, cs = (t & 7) * 32;
    const float* s = src + (size_t)(r0 + r) * FEAT + cs;
    #pragma unroll
    for (int i = 0; i < 8; ++i){
      f32x4 v = *(const f32x4*)(s + 4*i);
      tile[r][cs + 4*i + 0] = v[0];
      tile[r][cs + 4*i + 1] = v[1];
      tile[r][cs + 4*i + 2] = v[2];
      tile[r][cs + 4*i + 3] = v[3];
    }
  }
  __syncthreads();
  const int c = t;                    // output column 0..255
  const int kt = r0 >> 6, hh = (r0 >> 5) & 1, sc = swz(c);
  short* d = Bpack + (size_t)kt * TILE_SHORTS + hh * HALF_SHORTS + c * 32;
  #pragma unroll
  for (int i = 0; i < 4; ++i){        // k group r0+8i..+7
    s16x8 o;
    #pragma unroll
    for (int j = 0; j < 8; ++j) o[j] = f2bf(tile[8*i + j][c]);
    *(s16x8*)(d + ((i ^ sc) * 8)) = o;
  }
}

// ---------------------------------------------------------------------------
// Big GEMM, 8-phase (unchanged from round 8); P output bf16.
// ---------------------------------------------------------------------------
__global__ __launch_bounds__(512, 2) void k_gemm8p(const short* __restrict__ Apack,
                                                   const short* __restrict__ Bpack,
                                                   short* __restrict__ Pbase){
  __shared__ __align__(16) short lds[2][4][8192];  // [dbuf][A0,A1,B0,B1]

  const int t = threadIdx.x;
  const int w = t >> 6, l = t & 63;
  const int wm = w >> 2, wn = w & 3;
  const int lr = l & 15, lg = l >> 4;

  // bijective XCD-chunked swizzle of flat block id (235 = 8*29+3)
  int id = blockIdx.x;
  {
    const int xcd = id & 7, idx = id >> 3;
    id = (xcd < 3 ? xcd * 30 : 90 + (xcd - 3) * 29) + idx;
  }
  const int bm = id % NBM, s = id / NBM;
  const int row0 = bm * 256;
  const int u0  = (s < 3) ? s * 38 : 114 + (s - 3) * 37;  // tile index
  const int nst = (s < 3) ? 38 : 37;

  const char* Ab = (const char*)(Apack + (size_t)bm * NTILES * TILE_SHORTS);
  const char* Bb = (const char*)Bpack;
  const size_t tp = (size_t)t * 16;   // per-lane source offset within half-image

#define ST_AH(q, h, kt) do{                                                   \
    const char* s_ = Ab + (size_t)(kt) * 32768 + (h) * 16384 + tp;            \
    gl16(s_,        (char*)&lds[q][h][0] + w*1024);                           \
    gl16(s_ + 8192, (char*)&lds[q][h][0] + 8192 + w*1024); }while(0)
#define ST_BH(q, h, kt) do{                                                   \
    const char* s_ = Bb + (size_t)(kt) * 32768 + (h) * 16384 + tp;            \
    gl16(s_,        (char*)&lds[q][2+(h)][0] + w*1024);                       \
    gl16(s_ + 8192, (char*)&lds[q][2+(h)][0] + 8192 + w*1024); }while(0)

#define AF(q, h, mf) \
    (*(const s16x8*)&lds[q][h][ (wm*128 + (mf)*16 + lr) * 32 + \
      ((lg ^ swz(wm*128 + (mf)*16 + lr)) * 8) ])
#define BF(q, h, nf) \
    (*(const s16x8*)&lds[q][2+(h)][ (wn*64 + (nf)*16 + lr) * 32 + \
      ((lg ^ swz(wn*64 + (nf)*16 + lr)) * 8) ])

  f32x4 acc[8][4];
  #pragma unroll
  for (int m = 0; m < 8; ++m)
    #pragma unroll
    for (int n = 0; n < 4; ++n) acc[m][n] = (f32x4)(0.0f);

  // prologue: stage tile 0 (order Bk0, Ak0, Bk1, Ak1)
  ST_BH(0, 0, u0); ST_AH(0, 0, u0);
  ST_BH(0, 1, u0); ST_AH(0, 1, u0);
  VM4;    // Bk0+Ak0 landed; k1 halves stay in flight
  BARR;

  for (int t2 = 0; t2 < nst; ++t2){
    const int q = t2 & 1, qn = q ^ 1;
    const bool stg = (t2 + 1 < nst);
    const int ktn = u0 + t2 + 1;

    s16x8 bfr[4], af[4];

    // ---- P0: k0, m0-3 (+B reads); stage B-k0(next) ----
    #pragma unroll
    for (int n = 0; n < 4; ++n) bfr[n] = BF(q, 0, n);
    #pragma unroll
    for (int m = 0; m < 4; ++m) af[m] = AF(q, 0, m);
    if (stg) ST_BH(qn, 0, ktn);
    BARR;
    __builtin_amdgcn_s_setprio(1);
    #pragma unroll
    for (int m = 0; m < 4; ++m)
      #pragma unroll
      for (int n = 0; n < 4; ++n)
        acc[m][n] = mfma16(af[m], bfr[n], acc[m][n]);
    __builtin_amdgcn_s_setprio(0);
    BARR;

    // ---- P1: k0, m4-7 (B reused); stage A-k0(next) ----
    #pragma unroll
    for (int m = 0; m < 4; ++m) af[m] = AF(q, 0, m + 4);
    if (stg) ST_AH(qn, 0, ktn);
    BARR;
    __builtin_amdgcn_s_setprio(1);
    #pragma unroll
    for (int m = 0; m < 4; ++m)
      #pragma unroll
      for (int n = 0; n < 4; ++n)
        acc[m + 4][n] = mfma16(af[m], bfr[n], acc[m + 4][n]);
    __builtin_amdgcn_s_setprio(0);
    if (stg) { VM4; } else { VM0; }   // this tile's k1 halves landed
    BARR;

    // ---- P2: k1, m0-3 (+B reads); stage B-k1(next) ----
    #pragma unroll
    for (int n = 0; n < 4; ++n) bfr[n] = BF(q, 1, n);
    #pragma unroll
    for (int m = 0; m < 4; ++m) af[m] = AF(q, 1, m);
    if (stg) ST_BH(qn, 1, ktn);
    BARR;
    __builtin_amdgcn_s_setprio(1);
    #pragma unroll
    for (int m = 0; m < 4; ++m)
      #pragma unroll
      for (int n = 0; n < 4; ++n)
        acc[m][n] = mfma16(af[m], bfr[n], acc[m][n]);
    __builtin_amdgcn_s_setprio(0);
    BARR;

    // ---- P3: k1, m4-7 (B reused); stage A-k1(next) ----
    #pragma unroll
    for (int m = 0; m < 4; ++m) af[m] = AF(q, 1, m + 4);
    if (stg) ST_AH(qn, 1, ktn);
    BARR;
    __builtin_amdgcn_s_setprio(1);
    #pragma unroll
    for (int m = 0; m < 4; ++m)
      #pragma unroll
      for (int n = 0; n < 4; ++n)
        acc[m + 4][n] = mfma16(af[m], bfr[n], acc[m + 4][n]);
    __builtin_amdgcn_s_setprio(0);
    if (stg) { VM4; }                 // next tile's k0 halves landed
    BARR;
  }
#undef ST_AH
#undef ST_BH
#undef AF
#undef BF

  // epilogue: C/D layout col=lane&15, row=(lane>>4)*4+reg ; bf16 stores
  short* P = Pbase + (size_t)s * PSLABE;
  #pragma unroll
  for (int m = 0; m < 8; ++m){
    const int row = row0 + wm*128 + m*16 + lg*4;
    #pragma unroll
    for (int n = 0; n < 4; ++n){
      const int col = wn*64 + n*16 + lr;
      short* pp = P + (size_t)row * FEAT + col;
      #pragma unroll
      for (int r = 0; r < 4; ++r)
        if (row + r < M_ROWS) pp[(size_t)r * FEAT] = f2bf(acc[m][n][r]);
    }
  }
}

// ---------------------------------------------------------------------------
// Bpack = pack(transpose(l2norm_rows(relu((sum_s P[s]) @ W + b))))  (P bf16)
// ---------------------------------------------------------------------------
__global__ __launch_bounds__(256) void k_fused2(const short* __restrict__ Pb,
                                                const float* __restrict__ W,
                                                const float* __restrict__ b,
                                                short* __restrict__ Bpack){
  __shared__ float ylds[32][257];
  __shared__ float red[32][33];
  __shared__ float scale[32];
  const int t  = threadIdx.x;
  const int r0 = blockIdx.x * 32;     // output k-base (H row block)
  {
    const int r = t >> 3, cs = (t & 7) * 32;
    const size_t off = (size_t)(r0 + r) * FEAT + cs;
    float aa[32];
    {
      const short* p0 = Pb + off;
      #pragma unroll
      for (int i4 = 0; i4 < 4; ++i4){
        s16x8 v = *(const s16x8*)(p0 + i4*8);
        #pragma unroll
        for (int e = 0; e < 8; ++e) aa[i4*8 + e] = bf2f(v[e]);
      }
    }
    #pragma unroll
    for (int s = 1; s < NSLICE; ++s){
      const short* ps = Pb + (size_t)s * PSLABE + off;
      #pragma unroll
      for (int i4 = 0; i4 < 4; ++i4){
        s16x8 v = *(const s16x8*)(ps + i4*8);
        #pragma unroll
        for (int e = 0; e < 8; ++e) aa[i4*8 + e] += bf2f(v[e]);
      }
    }
    #pragma unroll
    for (int k = 0; k < 32; ++k) ylds[r][cs + k] = aa[k];
  }
  __syncthreads();

  const int rg = t >> 5;   // row group rg*4..+3 (k within block)
  const int cg = t & 31;   // col group cg*8..+7
  float acc[4][8];
  {
    float bias[8];
    #pragma unroll
    for (int j = 0; j < 8; ++j) bias[j] = b[cg*8 + j];
    #pragma unroll
    for (int i = 0; i < 4; ++i)
      #pragma unroll
      for (int j = 0; j < 8; ++j) acc[i][j] = bias[j];
  }

  #pragma unroll 4
  for (int k = 0; k < FEAT; ++k){
    float yv[4];
    #pragma unroll
    for (int i = 0; i < 4; ++i) yv[i] = ylds[rg*4 + i][k];
    f32x4 w0 = *(const f32x4*)(W + (size_t)k * FEAT + cg*8);
    f32x4 w1 = *(const f32x4*)(W + (size_t)k * FEAT + cg*8 + 4);
    #pragma unroll
    for (int i = 0; i < 4; ++i){
      #pragma unroll
      for (int j = 0; j < 4; ++j){
        acc[i][j]     += yv[i] * w0[j];
        acc[i][4 + j] += yv[i] * w1[j];
      }
    }
  }

  #pragma unroll
  for (int i = 0; i < 4; ++i){
    float ss = 0.0f;
    #pragma unroll
    for (int j = 0; j < 8; ++j){
      float v = fmaxf(acc[i][j], 0.0f);
      acc[i][j] = v;
      ss += v * v;
    }
    red[rg*4 + i][cg] = ss;
  }
  __syncthreads();
  if (t < 32){
    float ssum = 0.0f;
    #pragma unroll
    for (int j = 0; j < 32; ++j) ssum += red[t][j];
    scale[t] = 1.0f / fmaxf(sqrtf(ssum), 1e-12f);
  }
  __syncthreads();

  float sc[4];
  #pragma unroll
  for (int i = 0; i < 4; ++i) sc[i] = scale[rg*4 + i];

  // packed write: k = r0 + rg*4 + i, column c = cg*8 + j
  const int kb   = r0 + rg * 4;
  const int kt   = kb >> 6, hh = (kb >> 5) & 1, g = (kb >> 3) & 3, e0 = kb & 7;
  short* dbase = Bpack + (size_t)kt * TILE_SHORTS + hh * HALF_SHORTS;
  #pragma unroll
  for (int j = 0; j < 8; ++j){
    const int c = cg * 8 + j;
    s16x4 o;
    #pragma unroll
    for (int i = 0; i < 4; ++i) o[i] = f2bf(acc[i][j] * sc[i]);
    *(s16x4*)(dbase + c * 32 + ((g ^ swz(c)) * 8) + e0) = o;
  }
}

// ---------------------------------------------------------------------------
// out = (sum_s P[s]) @ W2 + b2    (12000 x 40), P bf16
// ---------------------------------------------------------------------------
__global__ __launch_bounds__(256) void k_final2(const short* __restrict__ Pb,
                                                const float* __restrict__ W2,
                                                const float* __restrict__ b2,
                                                float* __restrict__ out){
  __shared__ float ylds[32][257];
  const int t  = threadIdx.x;
  const int r0 = blockIdx.x * 32;
  {
    const int r = t >> 3, cs = (t & 7) * 32;
    const size_t off = (size_t)(r0 + r) * FEAT + cs;
    float aa[32];
    {
      const short* p0 = Pb + off;
      #pragma unroll
      for (int i4 = 0; i4 < 4; ++i4){
        s16x8 v = *(const s16x8*)(p0 + i4*8);
        #pragma unroll
        for (int e = 0; e < 8; ++e) aa[i4*8 + e] = bf2f(v[e]);
      }
    }
    #pragma unroll
    for (int s = 1; s < NSLICE; ++s){
      const short* ps = Pb + (size_t)s * PSLABE + off;
      #pragma unroll
      for (int i4 = 0; i4 < 4; ++i4){
        s16x8 v = *(const s16x8*)(ps + i4*8);
        #pragma unroll
        for (int e = 0; e < 8; ++e) aa[i4*8 + e] += bf2f(v[e]);
      }
    }
    #pragma unroll
    for (int k = 0; k < 32; ++k) ylds[r][cs + k] = aa[k];
  }
  __syncthreads();

  #pragma unroll
  for (int e = t; e < 32 * NCLS; e += 256){
    const int r = e / NCLS, n = e % NCLS;
    float a = b2[n];
    #pragma unroll 8
    for (int k = 0; k < FEAT; ++k)
      a = fmaf(ylds[r][k], W2[(size_t)k * NCLS + n], a);
    out[(size_t)(r0 + r) * NCLS + n] = a;
  }
}

// ---------------------------------------------------------------------------
extern "C" void kernel_launch(void* const* d_in, const int* in_sizes, int n_in,
                              void* d_out, int out_size, void* d_ws, size_t ws_size,
                              hipStream_t stream){
  const float* adj = (const float*)d_in[0];
  const float* x   = (const float*)d_in[1];
  const float* W0  = (const float*)d_in[2];
  const float* b0  = (const float*)d_in[3];
  const float* W1  = (const float*)d_in[4];
  const float* b1  = (const float*)d_in[5];
  const float* W2  = (const float*)d_in[6];
  const float* b2  = (const float*)d_in[7];
  float* out = (float*)d_out;

  char* ws = (char*)d_ws;
  const size_t BPACK_BYTES = (size_t)NTILES * TILE_SHORTS * 2;          //   6,160,384
  const size_t APACK_BYTES = (size_t)NBM * NTILES * TILE_SHORTS * 2;    // 289,538,048

  short* Bpack = (short*)ws;
  short* Apack = (short*)(ws + BPACK_BYTES);
  short* P     = (short*)(ws + BPACK_BYTES + APACK_BYTES);

  const dim3 b256(256), b512(512);

  k_pack<<<dim3(47, 47), b256, 0, stream>>>(adj, Apack);
  k_transpose_pack<<<376, b256, 0, stream>>>(x, Bpack);

  // layer 0
  k_gemm8p<<<NBM * NSLICE, b512, 0, stream>>>(Apack, Bpack, P);
  k_fused2<<<375, b256, 0, stream>>>(P, W0, b0, Bpack);
  // layer 1
  k_gemm8p<<<NBM * NSLICE, b512, 0, stream>>>(Apack, Bpack, P);
  k_fused2<<<375, b256, 0, stream>>>(P, W1, b1, Bpack);
  // layer 2
  k_gemm8p<<<NBM * NSLICE, b512, 0, stream>>>(Apack, Bpack, P);
  k_final2<<<375, b256, 0, stream>>>(P, W2, b2, out);
}

// Round 11
// 501.528 us; speedup vs baseline: 1.5663x; 1.1013x over previous
//
#include <hip/hip_runtime.h>
#include <hip/hip_bf16.h>

#define M_ROWS 12000
#define K_PAD  12032          // 188 * 64
#define FEAT   256
#define NCLS   40
#define NSLICE 5
#define NTILES 188            // K-tiles of 64
#define NBM    47             // M-tiles of 256
#define PSLABE (M_ROWS * FEAT)         // elements per P slab (bf16)
#define TILE_SHORTS 16384              // 32 KB tile image
#define HALF_SHORTS 8192

typedef __attribute__((ext_vector_type(4))) float f32x4;
typedef __attribute__((ext_vector_type(8))) short s16x8;
typedef __attribute__((ext_vector_type(4))) short s16x4;
typedef unsigned int u32;

__device__ __forceinline__ short f2bf(float f){
  __hip_bfloat16 h = __float2bfloat16(f);
  union { __hip_bfloat16 h; short s; } u; u.h = h; return u.s;
}
__device__ __forceinline__ float bf2f(short s){
  union { float f; u32 u; } v; v.u = ((u32)(unsigned short)s) << 16; return v.f;
}

__device__ __forceinline__ f32x4 mfma16(s16x8 a, s16x8 b, f32x4 c){
  return __builtin_amdgcn_mfma_f32_16x16x32_bf16(a, b, c, 0, 0, 0);
}

__device__ __forceinline__ void gl16(const void* g, void* l){
  __builtin_amdgcn_global_load_lds(
      (const __attribute__((address_space(1))) u32*)g,
      (__attribute__((address_space(3))) u32*)l, 16, 0, 0);
}

#define VM6   do { asm volatile("s_waitcnt vmcnt(6)" ::: "memory"); \
                   __builtin_amdgcn_sched_barrier(0); } while(0)
#define VM4   do { asm volatile("s_waitcnt vmcnt(4)" ::: "memory"); \
                   __builtin_amdgcn_sched_barrier(0); } while(0)
#define VM0   do { asm volatile("s_waitcnt vmcnt(0)" ::: "memory"); \
                   __builtin_amdgcn_sched_barrier(0); } while(0)
#define LGK0  do { asm volatile("s_waitcnt lgkmcnt(0)" ::: "memory"); \
                   __builtin_amdgcn_sched_barrier(0); } while(0)
#define BARR  do { __builtin_amdgcn_s_barrier(); \
                   __builtin_amdgcn_sched_barrier(0); } while(0)

__device__ __forceinline__ int swz(int r){ return (r & 3) ^ ((r >> 2) & 3); }

// ---------------------------------------------------------------------------
// fp32 x [12000][256] -> Bpack tile images (transposed, swizzle baked in).
// ---------------------------------------------------------------------------
__global__ __launch_bounds__(256) void k_transpose_pack(const float* __restrict__ src,
                                                        short* __restrict__ Bpack){
  const int t = threadIdx.x;
  if (blockIdx.x == 375){   // zero pad: k in [12000,12032)
    short* d = Bpack + (size_t)187 * TILE_SHORTS + HALF_SHORTS + t * 32;
    s16x8 z = (s16x8)0;
    #pragma unroll
    for (int i = 0; i < 4; ++i) *(s16x8*)(d + 8*i) = z;
    return;
  }
  __shared__ float tile[32][257];
  const int r0 = blockIdx.x * 32;     // k-base
  {
    const int r = t >> 3, cs = (t & 7) * 32;
    const float* s = src + (size_t)(r0 + r) * FEAT + cs;
    #pragma unroll
    for (int i = 0; i < 8; ++i){
      f32x4 v = *(const f32x4*)(s + 4*i);
      tile[r][cs + 4*i + 0] = v[0];
      tile[r][cs + 4*i + 1] = v[1];
      tile[r][cs + 4*i + 2] = v[2];
      tile[r][cs + 4*i + 3] = v[3];
    }
  }
  __syncthreads();
  const int c = t;                    // output column 0..255
  const int kt = r0 >> 6, hh = (r0 >> 5) & 1, sc = swz(c);
  short* d = Bpack + (size_t)kt * TILE_SHORTS + hh * HALF_SHORTS + c * 32;
  #pragma unroll
  for (int i = 0; i < 4; ++i){        // k group r0+8i..+7
    s16x8 o;
    #pragma unroll
    for (int j = 0; j < 8; ++j) o[j] = f2bf(tile[8*i + j][c]);
    *(s16x8*)(d + ((i ^ sc) * 8)) = o;
  }
}

// ---------------------------------------------------------------------------
// Layer-0 GEMM, fused with adj fp32->bf16 conversion + Apack emission.
// Same geometry/schedule as k_gemm8p; A-path is reg-staged (T14 split):
// P0/P1 issue next tile's fp32 A loads (4 f32x4 per half per thread) + B gl16;
// P2: vmcnt(6) -> cvt+ds_write+global_store A-k0(next);
// P3: vmcnt(0) -> cvt+ds_write+global_store A-k1(next), lgkmcnt(0).
// ---------------------------------------------------------------------------
__global__ __launch_bounds__(512, 2) void k_gemm_l0(const float* __restrict__ adj,
                                                    const short* __restrict__ Bpack,
                                                    short* __restrict__ Apack,
                                                    short* __restrict__ Pbase){
  __shared__ __align__(16) short lds[2][4][8192];  // [dbuf][A0,A1,B0,B1]

  const int t = threadIdx.x;
  const int w = t >> 6, l = t & 63;
  const int wm = w >> 2, wn = w & 3;
  const int lr = l & 15, lg = l >> 4;

  int id = blockIdx.x;
  {
    const int xcd = id & 7, idx = id >> 3;
    id = (xcd < 3 ? xcd * 30 : 90 + (xcd - 3) * 29) + idx;
  }
  const int bm = id % NBM, s = id / NBM;
  const int row0 = bm * 256;
  const int u0  = (s < 3) ? s * 38 : 114 + (s - 3) * 37;
  const int nst = (s < 3) ? 38 : 37;

  const char* Bb = (const char*)Bpack;
  const size_t tp = (size_t)t * 16;
  short* Aw = Apack + (size_t)bm * NTILES * TILE_SHORTS;

  // per-thread A source mapping: piece p (0,1): si = p*512+t, r=si>>2, sl=si&3
  size_t abase[2];      // row*M_ROWS + within-row swizzled slot offset
  #pragma unroll
  for (int p = 0; p < 2; ++p){
    const int si = p * 512 + t;
    const int r  = si >> 2, sl = si & 3;
    int grow = row0 + r; if (grow > M_ROWS - 1) grow = M_ROWS - 1;
    abase[p] = (size_t)grow * M_ROWS + (size_t)((sl ^ swz(r)) * 8);
  }

  f32x4 av0[4], av1[4];   // in-flight fp32 A halves (h=0 / h=1)

#define ISSUE_A0(kt) do{ \
    av0[0] = *(const f32x4*)(adj + abase[0] + (kt)*64);      \
    av0[1] = *(const f32x4*)(adj + abase[0] + (kt)*64 + 4);  \
    av0[2] = *(const f32x4*)(adj + abase[1] + (kt)*64);      \
    av0[3] = *(const f32x4*)(adj + abase[1] + (kt)*64 + 4); }while(0)
#define ISSUE_A1(kt) do{ \
    av1[0] = *(const f32x4*)(adj + abase[0] + (kt)*64 + 32);     \
    av1[1] = *(const f32x4*)(adj + abase[0] + (kt)*64 + 32 + 4); \
    av1[2] = *(const f32x4*)(adj + abase[1] + (kt)*64 + 32);     \
    av1[3] = *(const f32x4*)(adj + abase[1] + (kt)*64 + 32 + 4); }while(0)

#define CVT_WRITE_A(q, h, kt, AV) do{                                         \
    _Pragma("unroll")                                                         \
    for (int p = 0; p < 2; ++p){                                              \
      s16x8 o;                                                                \
      _Pragma("unroll")                                                       \
      for (int j = 0; j < 4; ++j){ o[j] = f2bf(AV[2*p][j]); o[4+j] = f2bf(AV[2*p+1][j]); } \
      const int si = p * 512 + t;                                             \
      *(s16x8*)&lds[q][h][si * 8] = o;                                        \
      *(s16x8*)(Aw + (size_t)(kt) * TILE_SHORTS + (h) * HALF_SHORTS + si * 8) = o; \
    } }while(0)

#define ST_BH(q, h, kt) do{                                                   \
    const char* s_ = Bb + (size_t)(kt) * 32768 + (h) * 16384 + tp;            \
    gl16(s_,        (char*)&lds[q][2+(h)][0] + w*1024);                       \
    gl16(s_ + 8192, (char*)&lds[q][2+(h)][0] + 8192 + w*1024); }while(0)

#define AF(q, h, mf) \
    (*(const s16x8*)&lds[q][h][ (wm*128 + (mf)*16 + lr) * 32 + \
      ((lg ^ swz(wm*128 + (mf)*16 + lr)) * 8) ])
#define BF(q, h, nf) \
    (*(const s16x8*)&lds[q][2+(h)][ (wn*64 + (nf)*16 + lr) * 32 + \
      ((lg ^ swz(wn*64 + (nf)*16 + lr)) * 8) ])

  f32x4 acc[8][4];
  #pragma unroll
  for (int m = 0; m < 8; ++m)
    #pragma unroll
    for (int n = 0; n < 4; ++n) acc[m][n] = (f32x4)(0.0f);

  // prologue: tile u0 -> buf 0
  ISSUE_A0(u0); ST_BH(0, 0, u0);   // 4 + 2 vm ops
  ISSUE_A1(u0); ST_BH(0, 1, u0);   // 4 + 2
  VM6;  CVT_WRITE_A(0, 0, u0, av0);
  VM0;  CVT_WRITE_A(0, 1, u0, av1);
  LGK0;
  BARR;

  for (int t2 = 0; t2 < nst; ++t2){
    const int q = t2 & 1, qn = q ^ 1;
    const bool stg = (t2 + 1 < nst);
    const int ktn = u0 + t2 + 1;

    s16x8 bfr[4], af[4];

    // ---- P0: k0, m0-3; issue A-k0(next) + stage B-k0(next) ----
    #pragma unroll
    for (int n = 0; n < 4; ++n) bfr[n] = BF(q, 0, n);
    #pragma unroll
    for (int m = 0; m < 4; ++m) af[m] = AF(q, 0, m);
    if (stg){ ISSUE_A0(ktn); ST_BH(qn, 0, ktn); }
    BARR;
    __builtin_amdgcn_s_setprio(1);
    #pragma unroll
    for (int m = 0; m < 4; ++m)
      #pragma unroll
      for (int n = 0; n < 4; ++n)
        acc[m][n] = mfma16(af[m], bfr[n], acc[m][n]);
    __builtin_amdgcn_s_setprio(0);
    BARR;

    // ---- P1: k0, m4-7 (B reused); issue A-k1(next) + stage B-k1(next) ----
    #pragma unroll
    for (int m = 0; m < 4; ++m) af[m] = AF(q, 0, m + 4);
    if (stg){ ISSUE_A1(ktn); ST_BH(qn, 1, ktn); }
    BARR;
    __builtin_amdgcn_s_setprio(1);
    #pragma unroll
    for (int m = 0; m < 4; ++m)
      #pragma unroll
      for (int n = 0; n < 4; ++n)
        acc[m + 4][n] = mfma16(af[m], bfr[n], acc[m + 4][n]);
    __builtin_amdgcn_s_setprio(0);
    BARR;

    // ---- P2: k1, m0-3; land+convert+write A-k0(next) ----
    #pragma unroll
    for (int n = 0; n < 4; ++n) bfr[n] = BF(q, 1, n);
    #pragma unroll
    for (int m = 0; m < 4; ++m) af[m] = AF(q, 1, m);
    if (stg){ VM6; CVT_WRITE_A(qn, 0, ktn, av0); }
    BARR;
    __builtin_amdgcn_s_setprio(1);
    #pragma unroll
    for (int m = 0; m < 4; ++m)
      #pragma unroll
      for (int n = 0; n < 4; ++n)
        acc[m][n] = mfma16(af[m], bfr[n], acc[m][n]);
    __builtin_amdgcn_s_setprio(0);
    BARR;

    // ---- P3: k1, m4-7; land+convert+write A-k1(next) ----
    #pragma unroll
    for (int m = 0; m < 4; ++m) af[m] = AF(q, 1, m + 4);
    if (stg){ VM0; CVT_WRITE_A(qn, 1, ktn, av1); }
    BARR;
    __builtin_amdgcn_s_setprio(1);
    #pragma unroll
    for (int m = 0; m < 4; ++m)
      #pragma unroll
      for (int n = 0; n < 4; ++n)
        acc[m + 4][n] = mfma16(af[m], bfr[n], acc[m + 4][n]);
    __builtin_amdgcn_s_setprio(0);
    if (stg) LGK0;
    BARR;
  }
#undef ISSUE_A0
#undef ISSUE_A1
#undef CVT_WRITE_A
#undef ST_BH
#undef AF
#undef BF

  // epilogue: C/D layout col=lane&15, row=(lane>>4)*4+reg ; bf16 stores
  short* P = Pbase + (size_t)s * PSLABE;
  #pragma unroll
  for (int m = 0; m < 8; ++m){
    const int row = row0 + wm*128 + m*16 + lg*4;
    #pragma unroll
    for (int n = 0; n < 4; ++n){
      const int col = wn*64 + n*16 + lr;
      short* pp = P + (size_t)row * FEAT + col;
      #pragma unroll
      for (int r = 0; r < 4; ++r)
        if (row + r < M_ROWS) pp[(size_t)r * FEAT] = f2bf(acc[m][n][r]);
    }
  }
}

// ---------------------------------------------------------------------------
// Big GEMM, 8-phase (unchanged); sources are packed images; P output bf16.
// ---------------------------------------------------------------------------
__global__ __launch_bounds__(512, 2) void k_gemm8p(const short* __restrict__ Apack,
                                                   const short* __restrict__ Bpack,
                                                   short* __restrict__ Pbase){
  __shared__ __align__(16) short lds[2][4][8192];  // [dbuf][A0,A1,B0,B1]

  const int t = threadIdx.x;
  const int w = t >> 6, l = t & 63;
  const int wm = w >> 2, wn = w & 3;
  const int lr = l & 15, lg = l >> 4;

  int id = blockIdx.x;
  {
    const int xcd = id & 7, idx = id >> 3;
    id = (xcd < 3 ? xcd * 30 : 90 + (xcd - 3) * 29) + idx;
  }
  const int bm = id % NBM, s = id / NBM;
  const int row0 = bm * 256;
  const int u0  = (s < 3) ? s * 38 : 114 + (s - 3) * 37;  // tile index
  const int nst = (s < 3) ? 38 : 37;

  const char* Ab = (const char*)(Apack + (size_t)bm * NTILES * TILE_SHORTS);
  const char* Bb = (const char*)Bpack;
  const size_t tp = (size_t)t * 16;

#define ST_AH(q, h, kt) do{                                                   \
    const char* s_ = Ab + (size_t)(kt) * 32768 + (h) * 16384 + tp;            \
    gl16(s_,        (char*)&lds[q][h][0] + w*1024);                           \
    gl16(s_ + 8192, (char*)&lds[q][h][0] + 8192 + w*1024); }while(0)
#define ST_BH(q, h, kt) do{                                                   \
    const char* s_ = Bb + (size_t)(kt) * 32768 + (h) * 16384 + tp;            \
    gl16(s_,        (char*)&lds[q][2+(h)][0] + w*1024);                       \
    gl16(s_ + 8192, (char*)&lds[q][2+(h)][0] + 8192 + w*1024); }while(0)

#define AF(q, h, mf) \
    (*(const s16x8*)&lds[q][h][ (wm*128 + (mf)*16 + lr) * 32 + \
      ((lg ^ swz(wm*128 + (mf)*16 + lr)) * 8) ])
#define BF(q, h, nf) \
    (*(const s16x8*)&lds[q][2+(h)][ (wn*64 + (nf)*16 + lr) * 32 + \
      ((lg ^ swz(wn*64 + (nf)*16 + lr)) * 8) ])

  f32x4 acc[8][4];
  #pragma unroll
  for (int m = 0; m < 8; ++m)
    #pragma unroll
    for (int n = 0; n < 4; ++n) acc[m][n] = (f32x4)(0.0f);

  ST_BH(0, 0, u0); ST_AH(0, 0, u0);
  ST_BH(0, 1, u0); ST_AH(0, 1, u0);
  VM4;
  BARR;

  for (int t2 = 0; t2 < nst; ++t2){
    const int q = t2 & 1, qn = q ^ 1;
    const bool stg = (t2 + 1 < nst);
    const int ktn = u0 + t2 + 1;

    s16x8 bfr[4], af[4];

    // ---- P0 ----
    #pragma unroll
    for (int n = 0; n < 4; ++n) bfr[n] = BF(q, 0, n);
    #pragma unroll
    for (int m = 0; m < 4; ++m) af[m] = AF(q, 0, m);
    if (stg) ST_BH(qn, 0, ktn);
    BARR;
    __builtin_amdgcn_s_setprio(1);
    #pragma unroll
    for (int m = 0; m < 4; ++m)
      #pragma unroll
      for (int n = 0; n < 4; ++n)
        acc[m][n] = mfma16(af[m], bfr[n], acc[m][n]);
    __builtin_amdgcn_s_setprio(0);
    BARR;

    // ---- P1 ----
    #pragma unroll
    for (int m = 0; m < 4; ++m) af[m] = AF(q, 0, m + 4);
    if (stg) ST_AH(qn, 0, ktn);
    BARR;
    __builtin_amdgcn_s_setprio(1);
    #pragma unroll
    for (int m = 0; m < 4; ++m)
      #pragma unroll
      for (int n = 0; n < 4; ++n)
        acc[m + 4][n] = mfma16(af[m], bfr[n], acc[m + 4][n]);
    __builtin_amdgcn_s_setprio(0);
    if (stg) { VM4; } else { VM0; }
    BARR;

    // ---- P2 ----
    #pragma unroll
    for (int n = 0; n < 4; ++n) bfr[n] = BF(q, 1, n);
    #pragma unroll
    for (int m = 0; m < 4; ++m) af[m] = AF(q, 1, m);
    if (stg) ST_BH(qn, 1, ktn);
    BARR;
    __builtin_amdgcn_s_setprio(1);
    #pragma unroll
    for (int m = 0; m < 4; ++m)
      #pragma unroll
      for (int n = 0; n < 4; ++n)
        acc[m][n] = mfma16(af[m], bfr[n], acc[m][n]);
    __builtin_amdgcn_s_setprio(0);
    BARR;

    // ---- P3 ----
    #pragma unroll
    for (int m = 0; m < 4; ++m) af[m] = AF(q, 1, m + 4);
    if (stg) ST_AH(qn, 1, ktn);
    BARR;
    __builtin_amdgcn_s_setprio(1);
    #pragma unroll
    for (int m = 0; m < 4; ++m)
      #pragma unroll
      for (int n = 0; n < 4; ++n)
        acc[m + 4][n] = mfma16(af[m], bfr[n], acc[m + 4][n]);
    __builtin_amdgcn_s_setprio(0);
    if (stg) { VM4; }
    BARR;
  }
#undef ST_AH
#undef ST_BH
#undef AF
#undef BF

  short* P = Pbase + (size_t)s * PSLABE;
  #pragma unroll
  for (int m = 0; m < 8; ++m){
    const int row = row0 + wm*128 + m*16 + lg*4;
    #pragma unroll
    for (int n = 0; n < 4; ++n){
      const int col = wn*64 + n*16 + lr;
      short* pp = P + (size_t)row * FEAT + col;
      #pragma unroll
      for (int r = 0; r < 4; ++r)
        if (row + r < M_ROWS) pp[(size_t)r * FEAT] = f2bf(acc[m][n][r]);
    }
  }
}

// ---------------------------------------------------------------------------
// Bpack = pack(transpose(l2norm_rows(relu((sum_s P[s]) @ W + b))))  (P bf16)
// ---------------------------------------------------------------------------
__global__ __launch_bounds__(256) void k_fused2(const short* __restrict__ Pb,
                                                const float* __restrict__ W,
                                                const float* __restrict__ b,
                                                short* __restrict__ Bpack){
  __shared__ float ylds[32][257];
  __shared__ float red[32][33];
  __shared__ float scale[32];
  const int t  = threadIdx.x;
  const int r0 = blockIdx.x * 32;     // output k-base (H row block)
  {
    const int r = t >> 3, cs = (t & 7) * 32;
    const size_t off = (size_t)(r0 + r) * FEAT + cs;
    float aa[32];
    {
      const short* p0 = Pb + off;
      #pragma unroll
      for (int i4 = 0; i4 < 4; ++i4){
        s16x8 v = *(const s16x8*)(p0 + i4*8);
        #pragma unroll
        for (int e = 0; e < 8; ++e) aa[i4*8 + e] = bf2f(v[e]);
      }
    }
    #pragma unroll
    for (int s = 1; s < NSLICE; ++s){
      const short* ps = Pb + (size_t)s * PSLABE + off;
      #pragma unroll
      for (int i4 = 0; i4 < 4; ++i4){
        s16x8 v = *(const s16x8*)(ps + i4*8);
        #pragma unroll
        for (int e = 0; e < 8; ++e) aa[i4*8 + e] += bf2f(v[e]);
      }
    }
    #pragma unroll
    for (int k = 0; k < 32; ++k) ylds[r][cs + k] = aa[k];
  }
  __syncthreads();

  const int rg = t >> 5;
  const int cg = t & 31;
  float acc[4][8];
  {
    float bias[8];
    #pragma unroll
    for (int j = 0; j < 8; ++j) bias[j] = b[cg*8 + j];
    #pragma unroll
    for (int i = 0; i < 4; ++i)
      #pragma unroll
      for (int j = 0; j < 8; ++j) acc[i][j] = bias[j];
  }

  #pragma unroll 4
  for (int k = 0; k < FEAT; ++k){
    float yv[4];
    #pragma unroll
    for (int i = 0; i < 4; ++i) yv[i] = ylds[rg*4 + i][k];
    f32x4 w0 = *(const f32x4*)(W + (size_t)k * FEAT + cg*8);
    f32x4 w1 = *(const f32x4*)(W + (size_t)k * FEAT + cg*8 + 4);
    #pragma unroll
    for (int i = 0; i < 4; ++i){
      #pragma unroll
      for (int j = 0; j < 4; ++j){
        acc[i][j]     += yv[i] * w0[j];
        acc[i][4 + j] += yv[i] * w1[j];
      }
    }
  }

  #pragma unroll
  for (int i = 0; i < 4; ++i){
    float ss = 0.0f;
    #pragma unroll
    for (int j = 0; j < 8; ++j){
      float v = fmaxf(acc[i][j], 0.0f);
      acc[i][j] = v;
      ss += v * v;
    }
    red[rg*4 + i][cg] = ss;
  }
  __syncthreads();
  if (t < 32){
    float ssum = 0.0f;
    #pragma unroll
    for (int j = 0; j < 32; ++j) ssum += red[t][j];
    scale[t] = 1.0f / fmaxf(sqrtf(ssum), 1e-12f);
  }
  __syncthreads();

  float sc[4];
  #pragma unroll
  for (int i = 0; i < 4; ++i) sc[i] = scale[rg*4 + i];

  const int kb   = r0 + rg * 4;
  const int kt   = kb >> 6, hh = (kb >> 5) & 1, g = (kb >> 3) & 3, e0 = kb & 7;
  short* dbase = Bpack + (size_t)kt * TILE_SHORTS + hh * HALF_SHORTS;
  #pragma unroll
  for (int j = 0; j < 8; ++j){
    const int c = cg * 8 + j;
    s16x4 o;
    #pragma unroll
    for (int i = 0; i < 4; ++i) o[i] = f2bf(acc[i][j] * sc[i]);
    *(s16x4*)(dbase + c * 32 + ((g ^ swz(c)) * 8) + e0) = o;
  }
}

// ---------------------------------------------------------------------------
// out = (sum_s P[s]) @ W2 + b2    (12000 x 40), P bf16
// ---------------------------------------------------------------------------
__global__ __launch_bounds__(256) void k_final2(const short* __restrict__ Pb,
                                                const float* __restrict__ W2,
                                                const float* __restrict__ b2,
                                                float* __restrict__ out){
  __shared__ float ylds[32][257];
  const int t  = threadIdx.x;
  const int r0 = blockIdx.x * 32;
  {
    const int r = t >> 3, cs = (t & 7) * 32;
    const size_t off = (size_t)(r0 + r) * FEAT + cs;
    float aa[32];
    {
      const short* p0 = Pb + off;
      #pragma unroll
      for (int i4 = 0; i4 < 4; ++i4){
        s16x8 v = *(const s16x8*)(p0 + i4*8);
        #pragma unroll
        for (int e = 0; e < 8; ++e) aa[i4*8 + e] = bf2f(v[e]);
      }
    }
    #pragma unroll
    for (int s = 1; s < NSLICE; ++s){
      const short* ps = Pb + (size_t)s * PSLABE + off;
      #pragma unroll
      for (int i4 = 0; i4 < 4; ++i4){
        s16x8 v = *(const s16x8*)(ps + i4*8);
        #pragma unroll
        for (int e = 0; e < 8; ++e) aa[i4*8 + e] += bf2f(v[e]);
      }
    }
    #pragma unroll
    for (int k = 0; k < 32; ++k) ylds[r][cs + k] = aa[k];
  }
  __syncthreads();

  #pragma unroll
  for (int e = t; e < 32 * NCLS; e += 256){
    const int r = e / NCLS, n = e % NCLS;
    float a = b2[n];
    #pragma unroll 8
    for (int k = 0; k < FEAT; ++k)
      a = fmaf(ylds[r][k], W2[(size_t)k * NCLS + n], a);
    out[(size_t)(r0 + r) * NCLS + n] = a;
  }
}

// ---------------------------------------------------------------------------
extern "C" void kernel_launch(void* const* d_in, const int* in_sizes, int n_in,
                              void* d_out, int out_size, void* d_ws, size_t ws_size,
                              hipStream_t stream){
  const float* adj = (const float*)d_in[0];
  const float* x   = (const float*)d_in[1];
  const float* W0  = (const float*)d_in[2];
  const float* b0  = (const float*)d_in[3];
  const float* W1  = (const float*)d_in[4];
  const float* b1  = (const float*)d_in[5];
  const float* W2  = (const float*)d_in[6];
  const float* b2  = (const float*)d_in[7];
  float* out = (float*)d_out;

  char* ws = (char*)d_ws;
  const size_t BPACK_BYTES = (size_t)NTILES * TILE_SHORTS * 2;          //   6,160,384
  const size_t APACK_BYTES = (size_t)NBM * NTILES * TILE_SHORTS * 2;    // 289,538,048

  short* Bpack = (short*)ws;
  short* Apack = (short*)(ws + BPACK_BYTES);
  short* P     = (short*)(ws + BPACK_BYTES + APACK_BYTES);

  const dim3 b256(256), b512(512);

  k_transpose_pack<<<376, b256, 0, stream>>>(x, Bpack);

  // layer 0: fused fp32 conversion + Apack emission + GEMM
  k_gemm_l0<<<NBM * NSLICE, b512, 0, stream>>>(adj, Bpack, Apack, P);
  k_fused2<<<375, b256, 0, stream>>>(P, W0, b0, Bpack);
  // layer 1
  k_gemm8p<<<NBM * NSLICE, b512, 0, stream>>>(Apack, Bpack, P);
  k_fused2<<<375, b256, 0, stream>>>(P, W1, b1, Bpack);
  // layer 2
  k_gemm8p<<<NBM * NSLICE, b512, 0, stream>>>(Apack, Bpack, P);
  k_final2<<<375, b256, 0, stream>>>(P, W2, b2, out);
}